// Round 14
// baseline (336.257 us; speedup 1.0000x reference)
//
#include <hip/hip_runtime.h>

#define BATCH 4096
#define TT 512
#define HH 64
#define BT 16      // batch rows per block (transposed MFMA: batch is the N dim, ALL outputs valid)
#define XS 516     // x_s row stride in floats
#define HS 72      // h buffer row stride in bf16

typedef __attribute__((ext_vector_type(8))) short short8;
typedef __attribute__((ext_vector_type(4))) float floatx4;

__device__ __forceinline__ unsigned short f2bf(float f) {   // RNE f32->bf16
    unsigned u = __float_as_uint(f);
    u = u + 0x7FFFu + ((u >> 16) & 1u);
    return (unsigned short)(u >> 16);
}

// TRANSPOSED MFMA, ZERO WASTE. R13's ledger: wall = VALU(651) + MFMA(275) +
// slack(150), pipes never overlap; MFMA was 2x inflated because BT=8 used half
// of every 16-row tile. Here gates^T = W_hh * h^T: A = W_hh tile (M=16 gate
// rows, in registers, prescaled), B = h^T (N=16 batch cols; ds_read pattern
// identical to before), C = gates(16) x batch(16) -> every output used.
// Wave w owns type-tiles T=0..3 covering n in [16w,16w+16): lane (q,c) gets
// 4 COMPLETE cells (batch c, n=16w+4q+r) -> act fully register-local, h-write
// is one packed b64 of 4 consecutive bf16. 8 MFMAs/wave/step (was 16/SIMD).
// Grid 256 = 1 blk/CU, 4 waves; R13 lookahead order + rcp-merged act kept.
__global__ __launch_bounds__(256, 1) void lstm_kernel(
    const float* __restrict__ x, const float* __restrict__ W_ih,
    const float* __restrict__ W_hh, const float* __restrict__ b_ih,
    const float* __restrict__ b_hh, const float* __restrict__ W_out,
    const float* __restrict__ b_out, float* __restrict__ out)
{
    __shared__ __align__(16) float x_s[BT * XS];             // 33 KB
    __shared__ __align__(16) unsigned short hb0[16 * HS];    // h_k, k even (all rows valid)
    __shared__ __align__(16) unsigned short hb1[16 * HS];    // h_k, k odd
    __shared__ __align__(16) float hf[BT * 65];

    const int tid = threadIdx.x;
    const int w = tid >> 6;       // wave 0..3 -> hidden n in [16w, 16w+16)
    const int l = tid & 63;
    const int q = l >> 4;
    const int c = l & 15;         // lane's batch column
    const int bbase = blockIdx.x * BT;

    // stage x[bbase..bbase+15][0..511] into LDS, coalesced float4
    for (int i = 0; i < 8; ++i) {
        int flat = i * 256 + tid;              // 2048 float4s
        int row = flat >> 7, c4 = flat & 127;
        const float4* xg = reinterpret_cast<const float4*>(x + (size_t)(bbase + row) * TT);
        float4 v = xg[c4];
        *reinterpret_cast<float4*>(&x_s[row * XS + c4 * 4]) = v;
    }
    for (int i = tid; i < 16 * HS; i += 256) { hb0[i] = 0; hb1[i] = 0; }

    const float L1 = 1.44269504089f;      // log2(e)
    const float L2 = 2.88539008178f;      // 2*log2(e)

    // A-fragments (persistent): W_hh rows for type T, n-range [16w,16w+16),
    // PRE-SCALED (i,f,o: -log2e ; g: +2log2e).
    // A-layout: lane (q,c) holds A[m=c][k=8q+j] -> row g = 64T+16w+c.
    short8 afr[4][2];
    float wih[16], bb[16];        // indexed [4T+r] for C-row g = 64T+16w+4q+r
    for (int T = 0; T < 4; ++T) {
        float sc = (T == 2) ? L2 : -L1;
        {   // A-frag rows use m=c
            int g = 64 * T + 16 * w + c;
            for (int ks = 0; ks < 2; ++ks) {
                const float* wp = W_hh + g * 64 + ks * 32 + q * 8;
                short8 v;
                #pragma unroll
                for (int j = 0; j < 8; ++j) v[j] = (short)f2bf(wp[j] * sc);
                afr[T][ks] = v;
            }
        }
        #pragma unroll
        for (int r = 0; r < 4; ++r) {   // C/D rows use m=4q+r
            int g = 64 * T + 16 * w + 4 * q + r;
            wih[4 * T + r] = W_ih[g] * sc;
            bb[4 * T + r] = (b_ih[g] + b_hh[g]) * sc;
        }
    }

    float cst[4] = {0.f, 0.f, 0.f, 0.f};  // c-state: cells (batch c, n=16w+4q+r)
    float hv[4];
    floatx4 acc[4];                        // acc[T][r]: gate type T, cell r

    const int boff = c * HS + q * 8;      // B-frag LDS offset (shorts) — h row = batch c
    const int woff = c * HS + 16 * w + 4 * q;  // h write: 4 consecutive bf16
    const float* xrow = &x_s[c * XS];     // lane's batch row of x
    float xv = xrow[0];

    __syncthreads();   // staging + zeroed h0 visible

    // Prologue: gates(0) = x_proj only (h(-1)=0)
    #pragma unroll
    for (int T = 0; T < 4; ++T)
        #pragma unroll
        for (int r = 0; r < 4; ++r)
            acc[T][r] = fmaf(xv, wih[4 * T + r], bb[4 * T + r]);

    #define ACT2(r0, r1) do {                                                   \
        float ei0 = __builtin_amdgcn_exp2f(acc[0][r0]);                         \
        float ef0 = __builtin_amdgcn_exp2f(acc[1][r0]);                         \
        float eg0 = __builtin_amdgcn_exp2f(acc[2][r0]);                         \
        float eo0 = __builtin_amdgcn_exp2f(acc[3][r0]);                         \
        float ei1 = __builtin_amdgcn_exp2f(acc[0][r1]);                         \
        float ef1 = __builtin_amdgcn_exp2f(acc[1][r1]);                         \
        float eg1 = __builtin_amdgcn_exp2f(acc[2][r1]);                         \
        float eo1 = __builtin_amdgcn_exp2f(acc[3][r1]);                         \
        float pf0 = 1.f + ef0, pg0 = (1.f + ei0) * (1.f + eg0);                 \
        float pf1 = 1.f + ef1, pg1 = (1.f + ei1) * (1.f + eg1);                 \
        float d0 = pf0 * pg0, d1 = pf1 * pg1;                                   \
        float rd = __builtin_amdgcn_rcpf(d0 * d1);                              \
        float num0 = fmaf(cst[r0], pg0, (eg0 - 1.f) * pf0);                     \
        float num1 = fmaf(cst[r1], pg1, (eg1 - 1.f) * pf1);                     \
        cst[r0] = num0 * d1 * rd;                                               \
        cst[r1] = num1 * d0 * rd;                                               \
        float ec0 = __builtin_amdgcn_exp2f(L2 * cst[r0]);                       \
        float ec1 = __builtin_amdgcn_exp2f(L2 * cst[r1]);                       \
        float e0 = (1.f + eo0) * (1.f + ec0);                                   \
        float e1 = (1.f + eo1) * (1.f + ec1);                                   \
        float re = __builtin_amdgcn_rcpf(e0 * e1);                              \
        hv[r0] = (ec0 - 1.f) * e1 * re;                                         \
        hv[r1] = (ec1 - 1.f) * e0 * re;                                         \
    } while (0)

    for (int k = 0; k < TT - 1; ++k) {
        unsigned short* dst = (k & 1) ? hb1 : hb0;

        // ---- act(k): 4 complete cells, rcp-merged in pairs ----
        ACT2(0, 1);
        ACT2(2, 3);

        // packed h-write: 4 consecutive bf16 -> one b64 store
        unsigned u0 = (unsigned)f2bf(hv[0]) | ((unsigned)f2bf(hv[1]) << 16);
        unsigned u1 = (unsigned)f2bf(hv[2]) | ((unsigned)f2bf(hv[3]) << 16);
        uint2 hu; hu.x = u0; hu.y = u1;
        *reinterpret_cast<uint2*>(&dst[woff]) = hu;

        xv = xrow[k + 1];   // hoisted: latency hides under the barrier

        __syncthreads();

        // ---- B-frags from h(k) + issue MFMA(k+1); drains under next barrier+act ----
        short8 b0 = *reinterpret_cast<const short8*>(dst + boff);
        short8 b1 = *reinterpret_cast<const short8*>(dst + boff + 32);
        #pragma unroll
        for (int T = 0; T < 4; ++T)
            #pragma unroll
            for (int r = 0; r < 4; ++r)
                acc[T][r] = fmaf(xv, wih[4 * T + r], bb[4 * T + r]);
        #pragma unroll
        for (int T = 0; T < 4; ++T) {
            acc[T] = __builtin_amdgcn_mfma_f32_16x16x32_bf16(afr[T][0], b0, acc[T], 0, 0, 0);
            acc[T] = __builtin_amdgcn_mfma_f32_16x16x32_bf16(afr[T][1], b1, acc[T], 0, 0, 0);
        }
    }

    // ---- final act(511) ----
    ACT2(0, 1);
    ACT2(2, 3);

    #pragma unroll
    for (int r = 0; r < 4; ++r) hf[c * 65 + 16 * w + 4 * q + r] = hv[r];
    __syncthreads();

    // head: out[b][o] = sum_n hf[b][n]*W_out[o][n] + b_out[o]
    if (tid < BT * 3) {
        int row = tid / 3, o = tid % 3;
        float s = b_out[o];
        #pragma unroll 8
        for (int k = 0; k < HH; ++k) s = fmaf(hf[row * 65 + k], W_out[o * 64 + k], s);
        out[(size_t)(bbase + row) * 3 + o] = s;
    }
    #undef ACT2
}

extern "C" void kernel_launch(void* const* d_in, const int* in_sizes, int n_in,
                              void* d_out, int out_size, void* d_ws, size_t ws_size,
                              hipStream_t stream) {
    const float* x     = (const float*)d_in[0];
    const float* W_ih  = (const float*)d_in[1];
    const float* W_hh  = (const float*)d_in[2];
    const float* b_ih  = (const float*)d_in[3];
    const float* b_hh  = (const float*)d_in[4];
    const float* W_out = (const float*)d_in[5];
    const float* b_out = (const float*)d_in[6];
    float* out = (float*)d_out;
    hipLaunchKernelGGL(lstm_kernel, dim3(BATCH / BT), dim3(256), 0, stream,
                       x, W_ih, W_hh, b_ih, b_hh, W_out, b_out, out);
}

// Round 15
// 257.557 us; speedup vs baseline: 1.3056x; 1.3056x over previous
//
#include <hip/hip_runtime.h>

#define BATCH 4096
#define TT 512
#define HH 64
#define BT 8       // batch rows per block; batch j at tile row 4*(j>>1)+(j&1) -> valid C/D slots r=0,1
#define XS 516     // x_s row stride in floats
#define HS 72      // h buffer row stride in bf16

typedef __attribute__((ext_vector_type(8))) short short8;
typedef __attribute__((ext_vector_type(4))) float floatx4;
typedef __attribute__((ext_vector_type(2))) float float2v;

__device__ __forceinline__ unsigned short f2bf(float f) {   // RNE f32->bf16
    unsigned u = __float_as_uint(f);
    u = u + 0x7FFFu + ((u >> 16) & 1u);
    return (unsigned short)(u >> 16);
}

// R13 (best: 231 us) + PACKED-F32 ACT. Ledger: wall 1081 = VALU 651 + MFMA 275
// + slack 155; MFMA & slack structurally pinned (R14 proved zero-waste needs
// 1 blk/CU which exposes ~600 idle). Attack VALU's full-rate half: the two
// cells' act dataflow is identical -> express as float2 vector ops so hipcc
// emits VOP3P v_pk_{add,mul,fma}_f32 (2 f32/inst): ~36 scalar -> ~16 packed
// insts/step; acc-init 8 fmaf -> 4 pk_fma. Trans (12/step) unchanged - that
// 384 cyc/SIMD is the hard floor of this problem.
__global__ __launch_bounds__(256, 2) void lstm_kernel(
    const float* __restrict__ x, const float* __restrict__ W_ih,
    const float* __restrict__ W_hh, const float* __restrict__ b_ih,
    const float* __restrict__ b_hh, const float* __restrict__ W_out,
    const float* __restrict__ b_out, float* __restrict__ out)
{
    __shared__ __align__(16) float x_s[BT * XS];             // 16.5 KB
    __shared__ __align__(16) unsigned short hb0[16 * HS];    // h_k, k even; rows m&2 stay 0
    __shared__ __align__(16) unsigned short hb1[16 * HS];    // h_k, k odd
    __shared__ __align__(16) float hf[BT * 65];

    const int tid = threadIdx.x;
    const int w = tid >> 6;       // wave 0..3 -> gate col-tiles {w,w+4,w+8,w+12}
    const int l = tid & 63;
    const int q = l >> 4;
    const int c = l & 15;
    const int n = 16 * w + c;     // hidden index this lane activates
    const int bbase = blockIdx.x * BT;

    // stage x[bbase..bbase+7][0..511] into LDS, coalesced float4
    for (int i = 0; i < 4; ++i) {
        int flat = i * 256 + tid;              // 1024 float4s
        int row = flat >> 7, c4 = flat & 127;
        const float4* xg = reinterpret_cast<const float4*>(x + (size_t)(bbase + row) * TT);
        float4 v = xg[c4];
        *reinterpret_cast<float4*>(&x_s[row * XS + c4 * 4]) = v;
    }
    for (int i = tid; i < 16 * HS; i += 256) { hb0[i] = 0; hb1[i] = 0; }

    const float L1 = 1.44269504089f;      // log2(e)
    const float L2 = 2.88539008178f;      // 2*log2(e)

    // persistent B-fragments, PRE-SCALED: t=0(i),1(f),3(o): -log2e ; t=2(g): +2log2e
    short8 bfr[4][2];
    float2v wih2[4], bb2[4];              // broadcast pairs for pk_fma acc-init
    for (int t = 0; t < 4; ++t) {
        float sc = (t == 2) ? L2 : -L1;
        int g = 64 * t + n;
        float wv = W_ih[g] * sc;
        float bv = (b_ih[g] + b_hh[g]) * sc;
        wih2[t] = float2v{wv, wv};
        bb2[t] = float2v{bv, bv};
        for (int ks = 0; ks < 2; ++ks) {
            const float* wp = W_hh + g * 64 + ks * 32 + q * 8;
            short8 v;
            #pragma unroll
            for (int j = 0; j < 8; ++j) v[j] = (short)f2bf(wp[j] * sc);
            bfr[t][ks] = v;
        }
    }

    float2v cst2 = {0.f, 0.f};    // c-state, batch rows {2q, 2q+1}, hidden n
    float2v hv2 = {0.f, 0.f};     // current h (register)
    const float2v one2 = {1.f, 1.f};
    const float2v L2v = {L2, L2};

    floatx4 acc[4];               // slots r=2,3 face zero A-rows: init once, stay 0
    #pragma unroll
    for (int t = 0; t < 4; ++t) acc[t] = floatx4{0.f, 0.f, 0.f, 0.f};

    const int aoff = c * HS + q * 8;      // A-frag LDS offset (shorts)
    const int woff = (4 * q) * HS + n;    // h write base; +HS for cell 1
    const float* xrowA = &x_s[(2 * q) * XS];
    const float* xrowB = &x_s[(2 * q + 1) * XS];

    __syncthreads();   // staging + zeroed h0 visible

    // Prologue: gates(0) = x_proj only (h(-1)=0 -> no MFMA needed)
    {
        float2v x01 = {xrowA[0], xrowB[0]};
        #pragma unroll
        for (int t = 0; t < 4; ++t) {
            float2v a2 = x01 * wih2[t] + bb2[t];
            acc[t][0] = a2.x; acc[t][1] = a2.y;
        }
    }

    // packed act: 8 scalar exp2 -> float2v algebra (pk ops) -> 2 scalar rcp
    #define ACTP() do {                                                         \
        float2v ei2, ef2, eg2, eo2;                                             \
        ei2.x = __builtin_amdgcn_exp2f(acc[0][0]);                              \
        ei2.y = __builtin_amdgcn_exp2f(acc[0][1]);                              \
        ef2.x = __builtin_amdgcn_exp2f(acc[1][0]);                              \
        ef2.y = __builtin_amdgcn_exp2f(acc[1][1]);                              \
        eg2.x = __builtin_amdgcn_exp2f(acc[2][0]);                              \
        eg2.y = __builtin_amdgcn_exp2f(acc[2][1]);                              \
        eo2.x = __builtin_amdgcn_exp2f(acc[3][0]);                              \
        eo2.y = __builtin_amdgcn_exp2f(acc[3][1]);                              \
        float2v pf2 = ef2 + one2;                                               \
        float2v pg2 = (ei2 + one2) * (eg2 + one2);                              \
        float2v d2 = pf2 * pg2;                                                 \
        float rd = __builtin_amdgcn_rcpf(d2.x * d2.y);                          \
        float2v num2 = cst2 * pg2 + (eg2 - one2) * pf2;                         \
        float2v dsw = {d2.y, d2.x};                                             \
        cst2 = num2 * dsw * rd;                                                 \
        float2v l2c = cst2 * L2v;                                               \
        float2v ec2;                                                            \
        ec2.x = __builtin_amdgcn_exp2f(l2c.x);                                  \
        ec2.y = __builtin_amdgcn_exp2f(l2c.y);                                  \
        float2v e2 = (eo2 + one2) * (ec2 + one2);                               \
        float re = __builtin_amdgcn_rcpf(e2.x * e2.y);                          \
        float2v esw = {e2.y, e2.x};                                             \
        hv2 = (ec2 - one2) * esw * re;                                          \
    } while (0)

    for (int k = 0; k < TT - 1; ++k) {
        unsigned short* dst = (k & 1) ? hb1 : hb0;

        ACTP();
        dst[woff] = f2bf(hv2.x);
        dst[woff + HS] = f2bf(hv2.y);

        // hoist x(k+1) LDS reads: latency hides under the barrier
        float2v x01 = {xrowA[k + 1], xrowB[k + 1]};

        __syncthreads();

        // ---- read h(k) frags + issue MFMA(k+1); drains under next barrier+act ----
        short8 a0 = *reinterpret_cast<const short8*>(dst + aoff);
        short8 a1 = *reinterpret_cast<const short8*>(dst + aoff + 32);
        #pragma unroll
        for (int t = 0; t < 4; ++t) {
            float2v a2 = x01 * wih2[t] + bb2[t];
            acc[t][0] = a2.x; acc[t][1] = a2.y;
        }
        #pragma unroll
        for (int t = 0; t < 4; ++t) {
            acc[t] = __builtin_amdgcn_mfma_f32_16x16x32_bf16(a0, bfr[t][0], acc[t], 0, 0, 0);
            acc[t] = __builtin_amdgcn_mfma_f32_16x16x32_bf16(a1, bfr[t][1], acc[t], 0, 0, 0);
        }
    }

    // ---- final act(511) ----
    ACTP();

    hf[(2 * q) * 65 + n] = hv2.x;
    hf[(2 * q + 1) * 65 + n] = hv2.y;
    __syncthreads();

    // head: out[b][o] = sum_n hf[b][n]*W_out[o][n] + b_out[o]
    if (tid < BT * 3) {
        int row = tid / 3, o = tid % 3;
        float s = b_out[o];
        #pragma unroll 8
        for (int k = 0; k < HH; ++k) s = fmaf(hf[row * 65 + k], W_out[o * 64 + k], s);
        out[(size_t)(bbase + row) * 3 + o] = s;
    }
    #undef ACTP
}

extern "C" void kernel_launch(void* const* d_in, const int* in_sizes, int n_in,
                              void* d_out, int out_size, void* d_ws, size_t ws_size,
                              hipStream_t stream) {
    const float* x     = (const float*)d_in[0];
    const float* W_ih  = (const float*)d_in[1];
    const float* W_hh  = (const float*)d_in[2];
    const float* b_ih  = (const float*)d_in[3];
    const float* b_hh  = (const float*)d_in[4];
    const float* W_out = (const float*)d_in[5];
    const float* b_out = (const float*)d_in[6];
    float* out = (float*)d_out;
    hipLaunchKernelGGL(lstm_kernel, dim3(BATCH / BT), dim3(256), 0, stream,
                       x, W_ih, W_hh, b_ih, b_hh, W_out, b_out, out);
}

// Round 16
// 247.037 us; speedup vs baseline: 1.3612x; 1.0426x over previous
//
#include <hip/hip_runtime.h>
#include <hip/hip_bf16.h>

#define BATCH 4096
#define TT 512
#define HH 64
#define BT 8       // batch rows per block; batch j at tile row 4*(j>>1)+(j&1) -> valid C/D slots r=0,1
#define XS 516     // x_s row stride in floats
#define HS 72      // h buffer row stride in bf16

typedef __attribute__((ext_vector_type(8))) short short8;
typedef __attribute__((ext_vector_type(4))) float floatx4;
typedef __attribute__((ext_vector_type(2))) float float2v;

__device__ __forceinline__ unsigned short f2bf(float f) {   // RNE f32->bf16 (weights, one-time)
    unsigned u = __float_as_uint(f);
    u = u + 0x7FFFu + ((u >> 16) & 1u);
    return (unsigned short)(u >> 16);
}

// R15 (best: 216 us; wall 1014 = VALU 546 + MFMA 270 + slack 198, pipes
// strictly additive — in-phase block lock is a stable attractor and the
// act->h->barrier->MFMA chain is unswappable). This round: last full-rate
// micro-cuts toward the ~950-cyc additive floor:
//  (a) one v_cvt_pk_bf16_f32 (__float22bfloat162_rn, same RNE) replaces the
//      two 4-inst scalar f2bf conversions of the h-write,
//  (b) manual 2x unroll -> compile-time h-buffer pointers, no k&1 select.
__global__ __launch_bounds__(256, 2) void lstm_kernel(
    const float* __restrict__ x, const float* __restrict__ W_ih,
    const float* __restrict__ W_hh, const float* __restrict__ b_ih,
    const float* __restrict__ b_hh, const float* __restrict__ W_out,
    const float* __restrict__ b_out, float* __restrict__ out)
{
    __shared__ __align__(16) float x_s[BT * XS];             // 16.5 KB
    __shared__ __align__(16) unsigned short hb0[16 * HS];    // h_k, k even; rows m&2 stay 0
    __shared__ __align__(16) unsigned short hb1[16 * HS];    // h_k, k odd
    __shared__ __align__(16) float hf[BT * 65];

    const int tid = threadIdx.x;
    const int w = tid >> 6;       // wave 0..3 -> gate col-tiles {w,w+4,w+8,w+12}
    const int l = tid & 63;
    const int q = l >> 4;
    const int c = l & 15;
    const int n = 16 * w + c;     // hidden index this lane activates
    const int bbase = blockIdx.x * BT;

    // stage x[bbase..bbase+7][0..511] into LDS, coalesced float4
    for (int i = 0; i < 4; ++i) {
        int flat = i * 256 + tid;              // 1024 float4s
        int row = flat >> 7, c4 = flat & 127;
        const float4* xg = reinterpret_cast<const float4*>(x + (size_t)(bbase + row) * TT);
        float4 v = xg[c4];
        *reinterpret_cast<float4*>(&x_s[row * XS + c4 * 4]) = v;
    }
    for (int i = tid; i < 16 * HS; i += 256) { hb0[i] = 0; hb1[i] = 0; }

    const float L1 = 1.44269504089f;      // log2(e)
    const float L2 = 2.88539008178f;      // 2*log2(e)

    // persistent B-fragments, PRE-SCALED: t=0(i),1(f),3(o): -log2e ; t=2(g): +2log2e
    short8 bfr[4][2];
    float2v wih2[4], bb2[4];              // broadcast pairs for pk_fma acc-init
    for (int t = 0; t < 4; ++t) {
        float sc = (t == 2) ? L2 : -L1;
        int g = 64 * t + n;
        float wv = W_ih[g] * sc;
        float bv = (b_ih[g] + b_hh[g]) * sc;
        wih2[t] = float2v{wv, wv};
        bb2[t] = float2v{bv, bv};
        for (int ks = 0; ks < 2; ++ks) {
            const float* wp = W_hh + g * 64 + ks * 32 + q * 8;
            short8 v;
            #pragma unroll
            for (int j = 0; j < 8; ++j) v[j] = (short)f2bf(wp[j] * sc);
            bfr[t][ks] = v;
        }
    }

    float2v cst2 = {0.f, 0.f};    // c-state, batch rows {2q, 2q+1}, hidden n
    float2v hv2 = {0.f, 0.f};     // current h (register)
    const float2v one2 = {1.f, 1.f};
    const float2v L2v = {L2, L2};

    floatx4 acc[4];               // slots r=2,3 face zero A-rows: init once, stay 0
    #pragma unroll
    for (int t = 0; t < 4; ++t) acc[t] = floatx4{0.f, 0.f, 0.f, 0.f};

    const int aoff = c * HS + q * 8;      // A-frag LDS offset (shorts)
    const int woff = (4 * q) * HS + n;    // h write base; +HS for cell 1
    const float* xrowA = &x_s[(2 * q) * XS];
    const float* xrowB = &x_s[(2 * q + 1) * XS];

    __syncthreads();   // staging + zeroed h0 visible

    // Prologue: gates(0) = x_proj only (h(-1)=0 -> no MFMA needed)
    {
        float2v x01 = {xrowA[0], xrowB[0]};
        #pragma unroll
        for (int t = 0; t < 4; ++t) {
            float2v a2 = x01 * wih2[t] + bb2[t];
            acc[t][0] = a2.x; acc[t][1] = a2.y;
        }
    }

    // packed act: 10 scalar exp2 -> float2v algebra (pk ops) -> 2 scalar rcp
    #define ACTP() do {                                                         \
        float2v ei2, ef2, eg2, eo2;                                             \
        ei2.x = __builtin_amdgcn_exp2f(acc[0][0]);                              \
        ei2.y = __builtin_amdgcn_exp2f(acc[0][1]);                              \
        ef2.x = __builtin_amdgcn_exp2f(acc[1][0]);                              \
        ef2.y = __builtin_amdgcn_exp2f(acc[1][1]);                              \
        eg2.x = __builtin_amdgcn_exp2f(acc[2][0]);                              \
        eg2.y = __builtin_amdgcn_exp2f(acc[2][1]);                              \
        eo2.x = __builtin_amdgcn_exp2f(acc[3][0]);                              \
        eo2.y = __builtin_amdgcn_exp2f(acc[3][1]);                              \
        float2v pf2 = ef2 + one2;                                               \
        float2v pg2 = (ei2 + one2) * (eg2 + one2);                              \
        float2v d2 = pf2 * pg2;                                                 \
        float rd = __builtin_amdgcn_rcpf(d2.x * d2.y);                          \
        float2v num2 = cst2 * pg2 + (eg2 - one2) * pf2;                         \
        float2v dsw = {d2.y, d2.x};                                             \
        cst2 = num2 * dsw * rd;                                                 \
        float2v l2c = cst2 * L2v;                                               \
        float2v ec2;                                                            \
        ec2.x = __builtin_amdgcn_exp2f(l2c.x);                                  \
        ec2.y = __builtin_amdgcn_exp2f(l2c.y);                                  \
        float2v e2 = (eo2 + one2) * (ec2 + one2);                               \
        float re = __builtin_amdgcn_rcpf(e2.x * e2.y);                          \
        float2v esw = {e2.y, e2.x};                                             \
        hv2 = (ec2 - one2) * esw * re;                                          \
    } while (0)

    // one pipelined step: act(k) -> packed h write -> barrier -> frag read +
    // MFMA(k+1). dst is a compile-time constant pointer at each call site.
    auto step = [&](int k, unsigned short* dst) {
        ACTP();
        // one v_cvt_pk_bf16_f32; stores lower to b16, upper to b16_d16_hi
        __hip_bfloat162 hpk = __float22bfloat162_rn(float2{hv2.x, hv2.y});
        dst[woff]      = *reinterpret_cast<unsigned short*>(&hpk.x);
        dst[woff + HS] = *reinterpret_cast<unsigned short*>(&hpk.y);

        // hoist x(k+1) LDS reads: latency hides under the barrier
        float2v x01 = {xrowA[k + 1], xrowB[k + 1]};

        __syncthreads();

        short8 a0 = *reinterpret_cast<const short8*>(dst + aoff);
        short8 a1 = *reinterpret_cast<const short8*>(dst + aoff + 32);
        #pragma unroll
        for (int t = 0; t < 4; ++t) {
            float2v a2 = x01 * wih2[t] + bb2[t];
            acc[t][0] = a2.x; acc[t][1] = a2.y;
        }
        #pragma unroll
        for (int t = 0; t < 4; ++t) {
            acc[t] = __builtin_amdgcn_mfma_f32_16x16x32_bf16(a0, bfr[t][0], acc[t], 0, 0, 0);
            acc[t] = __builtin_amdgcn_mfma_f32_16x16x32_bf16(a1, bfr[t][1], acc[t], 0, 0, 0);
        }
    };

    // steps 0..510 pipelined (write h(k), issue MFMA(k+1)); manual 2x unroll
    for (int k = 0; k < 510; k += 2) {
        step(k, hb0);         // even k -> hb0
        step(k + 1, hb1);     // odd  k -> hb1
    }
    step(510, hb0);

    // ---- final act(511) ----
    ACTP();

    hf[(2 * q) * 65 + n] = hv2.x;
    hf[(2 * q + 1) * 65 + n] = hv2.y;
    __syncthreads();

    // head: out[b][o] = sum_n hf[b][n]*W_out[o][n] + b_out[o]
    if (tid < BT * 3) {
        int row = tid / 3, o = tid % 3;
        float s = b_out[o];
        #pragma unroll 8
        for (int k = 0; k < HH; ++k) s = fmaf(hf[row * 65 + k], W_out[o * 64 + k], s);
        out[(size_t)(bbase + row) * 3 + o] = s;
    }
    #undef ACTP
}

extern "C" void kernel_launch(void* const* d_in, const int* in_sizes, int n_in,
                              void* d_out, int out_size, void* d_ws, size_t ws_size,
                              hipStream_t stream) {
    const float* x     = (const float*)d_in[0];
    const float* W_ih  = (const float*)d_in[1];
    const float* W_hh  = (const float*)d_in[2];
    const float* b_ih  = (const float*)d_in[3];
    const float* b_hh  = (const float*)d_in[4];
    const float* W_out = (const float*)d_in[5];
    const float* b_out = (const float*)d_in[6];
    float* out = (float*)d_out;
    hipLaunchKernelGGL(lstm_kernel, dim3(BATCH / BT), dim3(256), 0, stream,
                       x, W_ih, W_hh, b_ih, b_hh, W_out, b_out, out);
}